// Round 1
// baseline (362.018 us; speedup 1.0000x reference)
//
#include <hip/hip_runtime.h>

// ---------------------------------------------------------------------------
// MultiHeadAttention: B=2, S=2048, H=16, Dh=64, D=1024, causal mask, fp32 I/O.
// Pipeline: cast->bf16 | QKV proj (MFMA gemm) | flash attn (MFMA) | out proj.
// ---------------------------------------------------------------------------

#define B_   2
#define S_   2048
#define H_   16
#define DH_  64
#define D_   1024
#define M_   (B_ * S_)          // 4096 rows

typedef __attribute__((ext_vector_type(8))) short short8;
typedef __attribute__((ext_vector_type(4))) short short4_t;
typedef float v4f __attribute__((ext_vector_type(4)));

__device__ __forceinline__ short f2bf(float f) {
    union { float f; unsigned u; } v; v.f = f;
    unsigned r = v.u + 0x7fffu + ((v.u >> 16) & 1u);  // round-to-nearest-even
    return (short)(r >> 16);
}

// ---------------------------------------------------------------------------
// Kernel 1: cast X[4M] and Wq,Wk,Wv,Wo[1M each] fp32 -> bf16 (float4-vectorized)
// ---------------------------------------------------------------------------
__global__ __launch_bounds__(256) void cast_kernel(
    const float* __restrict__ X,
    const float* __restrict__ Wq, const float* __restrict__ Wk,
    const float* __restrict__ Wv, const float* __restrict__ Wo,
    short* __restrict__ Xb, short* __restrict__ Wb)
{
    const int NX4 = (M_ * D_) / 4;      // 1,048,576 float4s of X
    const int NW4 = (D_ * D_) / 4;      // 262,144 float4s per W
    int idx = blockIdx.x * 256 + threadIdx.x;   // grid sized exactly: 2,097,152

    const float* src; short* dst; int off;
    if (idx < NX4) { src = X; dst = Xb; off = idx; }
    else {
        int r = idx - NX4;
        int sel = r >> 18;              // NW4 = 2^18
        int o = r & (NW4 - 1);
        src = (sel == 0) ? Wq : (sel == 1) ? Wk : (sel == 2) ? Wv : Wo;
        dst = Wb + sel * (D_ * D_);
        off = o;
    }
    float4 f = ((const float4*)src)[off];
    short4_t s;
    s.x = f2bf(f.x); s.y = f2bf(f.y); s.z = f2bf(f.z); s.w = f2bf(f.w);
    *(short4_t*)(dst + (size_t)off * 4) = s;
}

// ---------------------------------------------------------------------------
// Kernel 2: C = A(bf16,[M,K]) @ W(bf16,[N,K])^T + bias.  128x128 tile, BK=64.
// MODE 0: bf16 out, head-split [bh][s][64]   (Q, K)
// MODE 1: bf16 out, head-split transposed [bh][64][s]  (V^T)
// MODE 2: fp32 out, [M,N]                    (final projection)
// ---------------------------------------------------------------------------
template<int MODE>
__global__ __launch_bounds__(256) void gemm_kernel(
    const short* __restrict__ A, const short* __restrict__ W,
    const float* __restrict__ bias, void* __restrict__ out,
    int M, int N, int K)
{
    __shared__ __align__(16) short As[128][72];
    __shared__ __align__(16) short Bs[128][72];

    const int t    = threadIdx.x;
    const int lane = t & 63;
    const int wave = t >> 6;
    const int m0 = blockIdx.y * 128;
    const int n0 = blockIdx.x * 128;
    const int wm = (wave >> 1) * 64;
    const int wn = (wave & 1) * 64;

    v4f acc[4][4] = {};

    const int lrow = t >> 3;          // 0..31
    const int lcol = (t & 7) * 8;     // bf16-element offset within BK

    for (int k0 = 0; k0 < K; k0 += 64) {
        __syncthreads();
        #pragma unroll
        for (int it = 0; it < 4; ++it) {
            int r = lrow + it * 32;
            *(uint4*)&As[r][lcol] = *(const uint4*)(A + (size_t)(m0 + r) * K + k0 + lcol);
            *(uint4*)&Bs[r][lcol] = *(const uint4*)(W + (size_t)(n0 + r) * K + k0 + lcol);
        }
        __syncthreads();
        #pragma unroll
        for (int kk = 0; kk < 2; ++kk) {
            const int fr = lane & 15;
            const int fo = kk * 32 + (lane >> 4) * 8;
            short8 af[4], bf[4];
            #pragma unroll
            for (int i = 0; i < 4; ++i) af[i] = *(const short8*)&As[wm + i * 16 + fr][fo];
            #pragma unroll
            for (int j = 0; j < 4; ++j) bf[j] = *(const short8*)&Bs[wn + j * 16 + fr][fo];
            #pragma unroll
            for (int i = 0; i < 4; ++i)
                #pragma unroll
                for (int j = 0; j < 4; ++j)
                    acc[i][j] = __builtin_amdgcn_mfma_f32_16x16x32_bf16(af[i], bf[j], acc[i][j], 0, 0, 0);
        }
    }

    // Epilogue.  C/D layout: col = lane&15, row = (lane>>4)*4 + r  [m89/m91]
    const int colb = n0 + wn + (lane & 15);
    const int rowb = m0 + wm + (lane >> 4) * 4;
    #pragma unroll
    for (int j = 0; j < 4; ++j) {
        int col = colb + j * 16;
        float bv = bias[col];
        #pragma unroll
        for (int i = 0; i < 4; ++i) {
            #pragma unroll
            for (int r = 0; r < 4; ++r) {
                int row = rowb + i * 16 + r;
                float v = acc[i][j][r] + bv;
                if (MODE == 2) {
                    ((float*)out)[(size_t)row * N + col] = v;
                } else {
                    int b = row >> 11, s = row & 2047, h = col >> 6, d = col & 63;
                    if (MODE == 0)
                        ((short*)out)[((size_t)((b << 4) + h) * S_ + s) * DH_ + d] = f2bf(v);
                    else
                        ((short*)out)[((size_t)((b << 4) + h) << 17) + ((size_t)d << 11) + s] = f2bf(v);
                }
            }
        }
    }
}

// ---------------------------------------------------------------------------
// Kernel 3: causal flash attention.
// Grid: (qt = S/64, bh = B*H).  Block 256 = 4 waves; wave w owns 16 q-rows.
// Q,K: [bh][s][64] bf16;  Vt: [bh][64][s] bf16;  ctx out: [b*s][1024] bf16.
// ---------------------------------------------------------------------------
__global__ __launch_bounds__(256) void attn_kernel(
    const short* __restrict__ Q, const short* __restrict__ Kh,
    const short* __restrict__ Vt, short* __restrict__ ctx)
{
    __shared__ __align__(16) short Ks[64][72];
    __shared__ __align__(16) short Vs[64][72];     // V^T tile: [d][kv]
    __shared__ __align__(16) short Ps[4][16][72];  // per-wave P round-trip

    const int t    = threadIdx.x;
    const int lane = t & 63;
    const int w    = t >> 6;
    const int qt   = blockIdx.x;
    const int bh   = blockIdx.y;
    const int q0   = qt * 64;
    const int qr0  = q0 + w * 16;

    // Q fragments (A-operand layout: m = lane&15, k = (lane>>4)*8 + j)
    short8 qf[2];
    {
        const short* qp = Q + ((size_t)bh * S_ + qr0 + (lane & 15)) * DH_;
        qf[0] = *(const short8*)(qp + ((lane >> 4) * 8));
        qf[1] = *(const short8*)(qp + 32 + ((lane >> 4) * 8));
    }

    float m_i[4], l_i[4];
    v4f o[4] = {};
    #pragma unroll
    for (int r = 0; r < 4; ++r) { m_i[r] = -1e30f; l_i[r] = 0.f; }

    const int lrow = t >> 3;
    const int lcol = (t & 7) * 8;

    for (int kt = 0; kt <= qt; ++kt) {
        const int kv0 = kt * 64;
        __syncthreads();
        #pragma unroll
        for (int it = 0; it < 2; ++it) {
            int r = lrow + it * 32;
            *(uint4*)&Ks[r][lcol] = *(const uint4*)(Kh + ((size_t)bh * S_ + kv0 + r) * DH_ + lcol);
            *(uint4*)&Vs[r][lcol] = *(const uint4*)(Vt + ((size_t)bh << 17) + ((size_t)r << 11) + kv0 + lcol);
        }
        __syncthreads();

        // S = Q K^T for this wave's 16 q-rows x 64 kv-cols
        v4f sc[4] = {};
        #pragma unroll
        for (int kk = 0; kk < 2; ++kk) {
            const int fo = kk * 32 + (lane >> 4) * 8;
            #pragma unroll
            for (int j = 0; j < 4; ++j) {
                short8 kf = *(const short8*)&Ks[j * 16 + (lane & 15)][fo];
                sc[j] = __builtin_amdgcn_mfma_f32_16x16x32_bf16(qf[kk], kf, sc[j], 0, 0, 0);
            }
        }

        // online softmax (C-layout: col = lane&15, row = (lane>>4)*4 + r)
        float p[4][4], rm[4];
        const int colb = kv0 + (lane & 15);
        const int rowb = qr0 + (lane >> 4) * 4;
        #pragma unroll
        for (int r = 0; r < 4; ++r) rm[r] = -1e30f;
        #pragma unroll
        for (int j = 0; j < 4; ++j) {
            int col = colb + j * 16;
            #pragma unroll
            for (int r = 0; r < 4; ++r) {
                float v = sc[j][r] * 0.125f;
                if (kt == qt && col > rowb + r) v = -1e30f;
                p[j][r] = v;
                rm[r] = fmaxf(rm[r], v);
            }
        }
        #pragma unroll
        for (int off = 1; off < 16; off <<= 1)
            #pragma unroll
            for (int r = 0; r < 4; ++r)
                rm[r] = fmaxf(rm[r], __shfl_xor(rm[r], off, 64));

        float alpha[4], rs[4];
        #pragma unroll
        for (int r = 0; r < 4; ++r) {
            float mn = fmaxf(m_i[r], rm[r]);
            alpha[r] = __expf(m_i[r] - mn);
            m_i[r] = mn;
            rs[r] = 0.f;
            #pragma unroll
            for (int j = 0; j < 4; ++j) {
                p[j][r] = __expf(p[j][r] - mn);
                rs[r] += p[j][r];
            }
        }
        #pragma unroll
        for (int off = 1; off < 16; off <<= 1)
            #pragma unroll
            for (int r = 0; r < 4; ++r)
                rs[r] += __shfl_xor(rs[r], off, 64);
        #pragma unroll
        for (int r = 0; r < 4; ++r) l_i[r] = l_i[r] * alpha[r] + rs[r];
        #pragma unroll
        for (int j = 0; j < 4; ++j)
            #pragma unroll
            for (int r = 0; r < 4; ++r)
                o[j][r] *= alpha[r];

        // P: C-layout -> LDS -> A-layout (wave-local round trip)
        #pragma unroll
        for (int j = 0; j < 4; ++j)
            #pragma unroll
            for (int r = 0; r < 4; ++r)
                Ps[w][(lane >> 4) * 4 + r][j * 16 + (lane & 15)] = f2bf(p[j][r]);

        // O += P V   (B-operand from Vs: B[k][n] = V[kv][d] = Vs[d][kv])
        #pragma unroll
        for (int kk = 0; kk < 2; ++kk) {
            const int fo = kk * 32 + (lane >> 4) * 8;
            short8 pf = *(const short8*)&Ps[w][lane & 15][fo];
            #pragma unroll
            for (int j = 0; j < 4; ++j) {
                short8 vf = *(const short8*)&Vs[j * 16 + (lane & 15)][fo];
                o[j] = __builtin_amdgcn_mfma_f32_16x16x32_bf16(pf, vf, o[j], 0, 0, 0);
            }
        }
    }

    // epilogue: ctx[b*2048+s][h*64 + d] = o / l
    const int b = bh >> 4, h = bh & 15;
    #pragma unroll
    for (int r = 0; r < 4; ++r) {
        float inv = 1.f / l_i[r];
        int s = qr0 + (lane >> 4) * 4 + r;
        size_t base = ((size_t)(b * S_ + s) << 10) + (h << 6);
        #pragma unroll
        for (int j = 0; j < 4; ++j)
            ctx[base + j * 16 + (lane & 15)] = f2bf(o[j][r] * inv);
    }
}

// ---------------------------------------------------------------------------
extern "C" void kernel_launch(void* const* d_in, const int* in_sizes, int n_in,
                              void* d_out, int out_size, void* d_ws, size_t ws_size,
                              hipStream_t stream) {
    const float* X  = (const float*)d_in[0];
    // d_in[1] = mask (causal tril; implemented analytically)
    const float* Wq = (const float*)d_in[2];
    const float* bq = (const float*)d_in[3];
    const float* Wk = (const float*)d_in[4];
    const float* bk = (const float*)d_in[5];
    const float* Wv = (const float*)d_in[6];
    const float* bv = (const float*)d_in[7];
    const float* Wo = (const float*)d_in[8];
    const float* bo = (const float*)d_in[9];
    float* out = (float*)d_out;

    short* ws  = (short*)d_ws;
    short* Xb  = ws;                          // 4,194,304 bf16
    short* Wb  = Xb + 4194304;                // 4 x 1,048,576 (Wq,Wk,Wv,Wo)
    short* Qh  = Wb + 4194304;                // [bh][s][64]
    short* Kb  = Qh + 4194304;                // [bh][s][64]
    short* Vt  = Kb + 4194304;                // [bh][64][s]
    short* Ctx = Vt + 4194304;                // [b*s][1024]

    cast_kernel<<<8192, 256, 0, stream>>>(X, Wq, Wk, Wv, Wo, Xb, Wb);

    dim3 gg(D_ / 128, M_ / 128);  // (8, 32)
    gemm_kernel<0><<<gg, 256, 0, stream>>>(Xb, Wb,               bq, Qh,  M_, D_, D_);
    gemm_kernel<0><<<gg, 256, 0, stream>>>(Xb, Wb + 1048576,     bk, Kb,  M_, D_, D_);
    gemm_kernel<1><<<gg, 256, 0, stream>>>(Xb, Wb + 2097152,     bv, Vt,  M_, D_, D_);

    attn_kernel<<<dim3(S_ / 64, B_ * H_), 256, 0, stream>>>(Qh, Kb, Vt, Ctx);

    gemm_kernel<2><<<gg, 256, 0, stream>>>(Ctx, Wb + 3145728,    bo, out, M_, D_, D_);
}